// Round 9
// baseline (13690.836 us; speedup 1.0000x reference)
//
#include <hip/hip_runtime.h>
#include <cstddef>

#define SLOPE 0.2f

typedef unsigned short u16;
typedef __attribute__((ext_vector_type(8))) short short8v;
typedef __attribute__((ext_vector_type(8))) __bf16 bf16x8;
typedef __attribute__((ext_vector_type(4))) float f32x4;

__device__ __forceinline__ u16 f2bf(float x) {
  unsigned u = __float_as_uint(x);
  unsigned r = (u + 0x7fffu + ((u >> 16) & 1u)) >> 16;  // RNE
  return (u16)r;
}
__device__ __forceinline__ float bf2f(u16 h) {
  return __uint_as_float(((unsigned)h) << 16);
}
// T1 XCD-chunked swizzle (m204 bijective form, nwg % 8 == 0):
__device__ __forceinline__ int xcd_swz(int orig, int cpx) {
  return (orig & 7) * cpx + (orig >> 3);
}

// ---------------- dec0: h0[b][128] = leaky(x @ W0^T + b0) ----------------
__global__ __launch_bounds__(256) void k_dec0(const float* __restrict__ x,
    const float* __restrict__ w, const float* __restrict__ bias,
    float* __restrict__ h0) {
  const int t = threadIdx.x, lane = t & 63, wv = t >> 6;
  const int b = blockIdx.x, co = blockIdx.y * 4 + wv;
  const float4 xv = *(const float4*)(x + b * 256 + lane * 4);
  const float4 wvv = *(const float4*)(w + (size_t)co * 256 + lane * 4);
  float s = xv.x * wvv.x + xv.y * wvv.y + xv.z * wvv.z + xv.w * wvv.w;
#pragma unroll
  for (int m = 32; m >= 1; m >>= 1) s += __shfl_xor(s, m);
  if (lane == 0) {
    float a = s + bias[co];
    h0[b * 128 + co] = a > 0.f ? a : SLOPE * a;
  }
}

// ---------------- L1: deconv 128->128, 1^3 -> 2^3 ----------------
// co-split x8: grid 512 (1-D, XCD-swizzled), 16 co + 16 batches per block.
// h1 layout: [p][b][vox(=cls)][128]
__global__ __launch_bounds__(256) void k_l1(const float* __restrict__ h0,
    const float* __restrict__ w1, const float* __restrict__ b1,
    float* __restrict__ h1) {
  __shared__ float wl[4][8][17];  // [ci-chunk][tap8][co16+pad]
  const int t = threadIdx.x;
  const int wg = xcd_swz(blockIdx.x, 64);  // 512 blocks: 64 per XCD chunk
  const int p = wg >> 3, cog = wg & 7;     // 8 p's per XCD, 8 co-groups each
  const int co = t & 15, b = t >> 4;       // 16 co x 16 batches
  const int cobase = cog * 16;
  float acc[8];
  const float bv = b1[p * 128 + cobase + co];
#pragma unroll
  for (int j = 0; j < 8; ++j) acc[j] = bv;

  for (int ci0 = 0; ci0 < 128; ci0 += 4) {
    __syncthreads();
    // stage 8 live taps for 16 co x 4 ci: 512 scalars, 2 per thread
#pragma unroll
    for (int g2 = 0; g2 < 2; ++g2) {
      const int g = t + g2 * 256;
      const int tp = g & 7, c = (g >> 3) & 15, cc = g >> 7;
      const int kd = 1 + ((tp >> 2) & 1), kh = 1 + ((tp >> 1) & 1), kw = 1 + (tp & 1);
      wl[cc][tp][c] =
          w1[(((size_t)p * 128 + ci0 + cc) * 128 + cobase + c) * 64 + kd * 16 + kh * 4 + kw];
    }
    __syncthreads();
    const float4 v = *(const float4*)(h0 + b * 128 + ci0);
    const float xr[4] = {v.x, v.y, v.z, v.w};
#pragma unroll
    for (int cls = 0; cls < 8; ++cls) {
#pragma unroll
      for (int cc = 0; cc < 4; ++cc)
        acc[cls] = fmaf(xr[cc], wl[cc][cls][co], acc[cls]);
    }
  }
#pragma unroll
  for (int cls = 0; cls < 8; ++cls) {
    float a = acc[cls];
    a = a > 0.f ? a : SLOPE * a;
    h1[(((size_t)p * 16 + b) * 8 + cls) * 128 + cobase + co] = a;
  }
}

// ---------------- L2: deconv 128->64, 2^3 -> 4^3, fp32 VALU, split-bf16 output ----------------
// cls-half split (pz = ch): grid 512 (1-D, XCD-swizzled) -> 2 blocks/CU.
// in [p][b][8][128] f32 -> out hi/lo bf16 [p][b][64][64]
template <int CIN, int DIN>
__global__ __launch_bounds__(256) void k_deconv_split(const float* __restrict__ in,
    const float* __restrict__ w, const float* __restrict__ bias,
    u16* __restrict__ ohi, u16* __restrict__ olo) {
  constexpr int DOUT = 2 * DIN;
  constexpr int NVOXI = DIN * DIN * DIN;
  constexpr int NVOXO = DOUT * DOUT * DOUT;
  __shared__ float inl[4][64][2];
  __shared__ float wl[2][64][65];
  const int t = threadIdx.x;
  const int wg = xcd_swz(blockIdx.x, 64);  // 512 blocks: 64 per XCD chunk
  const int p = wg >> 3, bg = (wg >> 1) & 3, ch = wg & 1;  // 8 p's per XCD
  const int pz = ch;  // this block's z-parity (cls = ch*4 + c2)
  const int co = t & 63, sl = t >> 6;
  const int b = bg * 4 + sl;

  const int sv = t & 63;
  const int lz = sv >> 4, ly = (sv >> 2) & 3, lx = sv & 3;
  const int iz = lz - 1, iy = ly - 1, ix = lx - 1;  // tile base -1 (single tile)
  const bool okst = (unsigned)iz < (unsigned)DIN && (unsigned)iy < (unsigned)DIN &&
                    (unsigned)ix < (unsigned)DIN;
  const float* stp =
      in + (((size_t)p * 16 + b) * NVOXI + ((iz * DIN + iy) * DIN + ix)) * CIN;

  float acc[4][8];
  const float bv = bias[p * 64 + co];
#pragma unroll
  for (int c = 0; c < 4; ++c)
#pragma unroll
    for (int v = 0; v < 8; ++v) acc[c][v] = bv;

  for (int ci0 = 0; ci0 < CIN; ci0 += 2) {
    __syncthreads();
    {
      float2 v = make_float2(0.f, 0.f);
      if (okst) v = *(const float2*)(stp + ci0);
      *(float2*)&inl[sl][sv][0] = v;
    }
#pragma unroll
    for (int g4 = 0; g4 < 8; ++g4) {
      const int g = t + g4 * 256;
      const int t4 = g & 15, c = (g >> 4) & 63, cc = g >> 10;
      const float4 v =
          *(const float4*)(w + (((size_t)p * CIN + ci0 + cc) * 64 + c) * 64 + t4 * 4);
      wl[cc][t4 * 4 + 0][c] = v.x; wl[cc][t4 * 4 + 1][c] = v.y;
      wl[cc][t4 * 4 + 2][c] = v.z; wl[cc][t4 * 4 + 3][c] = v.w;
    }
    __syncthreads();
#pragma unroll
    for (int c2 = 0; c2 < 4; ++c2) {
      const int py = (c2 >> 1) & 1, px = c2 & 1;
      float in3[2][3][3][3];
#pragma unroll
      for (int az = 0; az < 3; ++az)
#pragma unroll
        for (int ay = 0; ay < 3; ++ay)
#pragma unroll
          for (int ax = 0; ax < 3; ++ax) {
            const int vf = ((pz + az) * 4 + (py + ay)) * 4 + (px + ax);
            const float2 v2 = *(const float2*)&inl[sl][vf][0];
            in3[0][az][ay][ax] = v2.x;
            in3[1][az][ay][ax] = v2.y;
          }
#pragma unroll
      for (int s = 0; s < 8; ++s) {
        const int sz = (s >> 2) & 1, sy = (s >> 1) & 1, sx = s & 1;
        const int tap =
            (3 - pz - 2 * sz) * 16 + (3 - py - 2 * sy) * 4 + (3 - px - 2 * sx);
#pragma unroll
        for (int cc = 0; cc < 2; ++cc) {
          const float wv = wl[cc][tap][co];
#pragma unroll
          for (int v = 0; v < 8; ++v) {
            const int vz = (v >> 2) & 1, vy = (v >> 1) & 1, vx = v & 1;
            acc[c2][v] = fmaf(in3[cc][vz + sz][vy + sy][vx + sx], wv, acc[c2][v]);
          }
        }
      }
    }
  }
#pragma unroll
  for (int c2 = 0; c2 < 4; ++c2) {
    const int py = (c2 >> 1) & 1, px = c2 & 1;
#pragma unroll
    for (int v = 0; v < 8; ++v) {
      const int vz = (v >> 2) & 1, vy = (v >> 1) & 1, vx = v & 1;
      const int oz = 2 * vz + pz, oy = 2 * vy + py, ox = 2 * vx + px;
      float a = acc[c2][v];
      a = a > 0.f ? a : SLOPE * a;
      const size_t idx =
          (((size_t)p * 16 + b) * NVOXO + (oz * DOUT + oy) * DOUT + ox) * 64 + co;
      const u16 hi = f2bf(a);
      ohi[idx] = hi;
      olo[idx] = f2bf(a - bf2f(hi));
    }
  }
}

// ---------------- prep: w3 [p][ci][co][tap] f32 -> wt3 hi/lo bf16 [p][tap][co][ci] ----------------
// cg-split x8: grid 512 (1-D, XCD-swizzled), 8 co per block.
__global__ __launch_bounds__(256) void k_prep_w3(const float* __restrict__ w3,
    u16* __restrict__ whi, u16* __restrict__ wlo) {
  __shared__ float tr[64][65];  // [tap][ci]
  const int t = threadIdx.x;
  const int wg = xcd_swz(blockIdx.x, 64);  // 512 blocks
  const int p = wg >> 3, cg = wg & 7;
  for (int c = 0; c < 8; ++c) {
    const int co = cg * 8 + c;
    __syncthreads();
#pragma unroll
    for (int it = 0; it < 4; ++it) {
      const int idx = t + it * 256;           // 1024 float4 slots: ci(64) x tq(16)
      const int ci = idx >> 4, tq = idx & 15;
      const float4 v = *(const float4*)(w3 + (((size_t)p * 64 + ci) * 64 + co) * 64 + tq * 4);
      tr[tq * 4 + 0][ci] = v.x; tr[tq * 4 + 1][ci] = v.y;
      tr[tq * 4 + 2][ci] = v.z; tr[tq * 4 + 3][ci] = v.w;
    }
    __syncthreads();
    const int tap = t >> 2, cq = t & 3;       // thread: 16 ci
    u16 hi[16], lo[16];
#pragma unroll
    for (int j = 0; j < 16; ++j) {
      const float v = tr[tap][cq * 16 + j];
      hi[j] = f2bf(v);
      lo[j] = f2bf(v - bf2f(hi[j]));
    }
    const size_t ob = (((size_t)p * 64 + tap) * 64 + co) * 64 + cq * 16;
#pragma unroll
    for (int h = 0; h < 2; ++h) {
      *(short8v*)(whi + ob + h * 8) = *(const short8v*)&hi[h * 8];
      *(short8v*)(wlo + ob + h * 8) = *(const short8v*)&lo[h * 8];
    }
  }
}

// ---------------- L3 via MFMA: 64->64, 4^3 -> 8^3, split-bf16, T14 async-stage ----------------
#define ASTR 40  // LDS row stride in shorts (80B = 5 x 16B units -> conflict-free)
struct L3Stage {
  short8v vh[4], vl[4], bh, bl;
};
__global__ __launch_bounds__(256, 2) void k_l3_mfma(const u16* __restrict__ inhi,
    const u16* __restrict__ inlo, const u16* __restrict__ whi,
    const u16* __restrict__ wlo, const float* __restrict__ bias,
    float* __restrict__ out) {
  __shared__ __align__(16) short Ah[256 * ASTR];
  __shared__ __align__(16) short Al[256 * ASTR];
  __shared__ __align__(16) short Bh[64 * ASTR];
  __shared__ __align__(16) short Bl[64 * ASTR];
  const int t = threadIdx.x;
  const int wg = xcd_swz(blockIdx.x, 256);  // 2048 blocks: 256 per XCD chunk
  const int p = wg >> 5, cls = (wg >> 2) & 7, bg = wg & 3;  // 8 p's per XCD
  const int pz = (cls >> 2) & 1, py = (cls >> 1) & 1, px = cls & 1;
  const int lane = t & 63, wv = t >> 6;
  const int b = bg * 4 + wv;

  const int r = t;
  const int rb = bg * 4 + (r >> 6);
  const int cv = r & 63, vz = cv >> 4, vy = (cv >> 2) & 3, vx = cv & 3;
  const int sco = t >> 2, skq = t & 3;

  auto issue = [&](int kt, L3Stage& st) {
    const int s = kt >> 1, ci0 = (kt & 1) * 32;
    const int sz = (s >> 2) & 1, sy = (s >> 1) & 1, sx = s & 1;
    const int tap = (3 - pz - 2 * sz) * 16 + (3 - py - 2 * sy) * 4 + (3 - px - 2 * sx);
    const int iz = vz + pz + sz - 1, iy = vy + py + sy - 1, ix = vx + px + sx - 1;
    const bool ok = (unsigned)iz < 4u && (unsigned)iy < 4u && (unsigned)ix < 4u;
    if (ok) {
      const size_t base =
          (((size_t)p * 16 + rb) * 64 + (iz * 4 + iy) * 4 + ix) * 64 + ci0;
#pragma unroll
      for (int j = 0; j < 4; ++j) {
        st.vh[j] = *(const short8v*)(inhi + base + j * 8);
        st.vl[j] = *(const short8v*)(inlo + base + j * 8);
      }
    } else {
#pragma unroll
      for (int j = 0; j < 4; ++j) { st.vh[j] = (short8v)0; st.vl[j] = (short8v)0; }
    }
    const size_t wb = (((size_t)p * 64 + tap) * 64 + sco) * 64 + ci0 + skq * 8;
    st.bh = *(const short8v*)(whi + wb);
    st.bl = *(const short8v*)(wlo + wb);
  };

  f32x4 acc[4][4];
#pragma unroll
  for (int nf = 0; nf < 4; ++nf) {
    const float bv = bias[p * 64 + nf * 16 + (lane & 15)];
#pragma unroll
    for (int mf = 0; mf < 4; ++mf) acc[mf][nf] = {bv, bv, bv, bv};
  }

  L3Stage cur, nxt;
  issue(0, cur);
  for (int kt = 0; kt < 16; ++kt) {
    __syncthreads();
    if (kt < 15) issue(kt + 1, nxt);
#pragma unroll
    for (int j = 0; j < 4; ++j) {
      *(short8v*)&Ah[r * ASTR + j * 8] = cur.vh[j];
      *(short8v*)&Al[r * ASTR + j * 8] = cur.vl[j];
    }
    *(short8v*)&Bh[sco * ASTR + skq * 8] = cur.bh;
    *(short8v*)&Bl[sco * ASTR + skq * 8] = cur.bl;
    __syncthreads();
    const int fr = lane & 15, kq = lane >> 4;
    short8v a_h[4], a_l[4];
#pragma unroll
    for (int mf = 0; mf < 4; ++mf) {
      const int row = wv * 64 + mf * 16 + fr;
      a_h[mf] = *(const short8v*)&Ah[row * ASTR + kq * 8];
      a_l[mf] = *(const short8v*)&Al[row * ASTR + kq * 8];
    }
#pragma unroll
    for (int nf = 0; nf < 4; ++nf) {
      const int col = nf * 16 + fr;
      const short8v b_h = *(const short8v*)&Bh[col * ASTR + kq * 8];
      const short8v b_l = *(const short8v*)&Bl[col * ASTR + kq * 8];
#pragma unroll
      for (int mf = 0; mf < 4; ++mf) {
        acc[mf][nf] = __builtin_amdgcn_mfma_f32_16x16x32_bf16(
            __builtin_bit_cast(bf16x8, a_h[mf]), __builtin_bit_cast(bf16x8, b_h),
            acc[mf][nf], 0, 0, 0);
        acc[mf][nf] = __builtin_amdgcn_mfma_f32_16x16x32_bf16(
            __builtin_bit_cast(bf16x8, a_h[mf]), __builtin_bit_cast(bf16x8, b_l),
            acc[mf][nf], 0, 0, 0);
        acc[mf][nf] = __builtin_amdgcn_mfma_f32_16x16x32_bf16(
            __builtin_bit_cast(bf16x8, a_l[mf]), __builtin_bit_cast(bf16x8, b_h),
            acc[mf][nf], 0, 0, 0);
      }
    }
    if (kt < 15) cur = nxt;
  }
#pragma unroll
  for (int mf = 0; mf < 4; ++mf) {
#pragma unroll
    for (int nf = 0; nf < 4; ++nf) {
      const int co = nf * 16 + (lane & 15);
#pragma unroll
      for (int rg = 0; rg < 4; ++rg) {
        const int mvox = mf * 16 + (lane >> 4) * 4 + rg;
        const int mz = mvox >> 4, my = (mvox >> 2) & 3, mx = mvox & 3;
        const int ovox = ((2 * mz + pz) * 8 + (2 * my + py)) * 8 + (2 * mx + px);
        float a = acc[mf][nf][rg];
        a = a > 0.f ? a : SLOPE * a;
        out[(((size_t)p * 16 + b) * 512 + ovox) * 64 + co] = a;
      }
    }
  }
}

// ---------------- L4: deconv 64->4, 8^3 -> 16^3 (scatter-register form) ----------------
// in: h3 [p][b][512][64] f32; out: [b][p][4][16][16][16]
// 1-D grid 2048 = XCD-swizzled (p, b, zhalf); block 256; thread = one class-position.
__global__ __launch_bounds__(256, 4) void k_l4(const float* __restrict__ in,
    const float* __restrict__ w4, const float* __restrict__ b4,
    float* __restrict__ out) {
  __shared__ float pl[4][520];    // ci-planes; [*][512] = zero slot
  __shared__ float wl[4][64][4];  // [ci][tap][co]
  const int t = threadIdx.x;
  const int wg = xcd_swz(blockIdx.x, 256);
  const int p = wg >> 5, b = (wg >> 1) & 15, zh = wg & 1;
  const int vz = zh * 4 + (t >> 6), vy = (t >> 3) & 7, vx = t & 7;

  if (t < 4) pl[t][512] = 0.f;  // zero slot (set once; planes only overwrite [0..511])

  int off[27];
#pragma unroll
  for (int a = 0; a < 27; ++a) {
    const int az = a / 9, ay = (a / 3) % 3, ax = a % 3;
    const int iz = vz + az - 1, iy = vy + ay - 1, ix = vx + ax - 1;
    const bool ok = (unsigned)iz < 8u && (unsigned)iy < 8u && (unsigned)ix < 8u;
    off[a] = ok ? (iz * 64 + iy * 8 + ix) : 512;
  }

  float acc[8][4];
  {
    const float4 bv = *(const float4*)(b4 + p * 4);
#pragma unroll
    for (int cls = 0; cls < 8; ++cls) {
      acc[cls][0] = bv.x; acc[cls][1] = bv.y; acc[cls][2] = bv.z; acc[cls][3] = bv.w;
    }
  }

  const float* gin = in + ((size_t)p * 16 + b) * 512 * 64;
  for (int ci0 = 0; ci0 < 64; ci0 += 4) {
    __syncthreads();
#pragma unroll
    for (int g2 = 0; g2 < 2; ++g2) {
      const int iv = t + g2 * 256;
      const float4 v = *(const float4*)(gin + (size_t)iv * 64 + ci0);
      pl[0][iv] = v.x; pl[1][iv] = v.y; pl[2][iv] = v.z; pl[3][iv] = v.w;
    }
    {
      const int ci = t >> 6, c2 = (t >> 4) & 3, tq = t & 15;
      const float4 v =
          *(const float4*)(w4 + (((size_t)p * 64 + ci0 + ci) * 4 + c2) * 64 + tq * 4);
      wl[ci][tq * 4 + 0][c2] = v.x; wl[ci][tq * 4 + 1][c2] = v.y;
      wl[ci][tq * 4 + 2][c2] = v.z; wl[ci][tq * 4 + 3][c2] = v.w;
    }
    __syncthreads();
#pragma unroll
    for (int ci = 0; ci < 4; ++ci) {
      float i3[27];
#pragma unroll
      for (int a = 0; a < 27; ++a) i3[a] = pl[ci][off[a]];
#pragma unroll
      for (int cls = 0; cls < 8; ++cls) {
        const int pz = (cls >> 2) & 1, py = (cls >> 1) & 1, px = cls & 1;
#pragma unroll
        for (int s = 0; s < 8; ++s) {
          const int sz = (s >> 2) & 1, sy = (s >> 1) & 1, sx = s & 1;
          const int a = (pz + sz) * 9 + (py + sy) * 3 + (px + sx);
          const int tap =
              (3 - pz - 2 * sz) * 16 + (3 - py - 2 * sy) * 4 + (3 - px - 2 * sx);
          const float4 wv = *(const float4*)&wl[ci][tap][0];  // b128 broadcast
          acc[cls][0] = fmaf(i3[a], wv.x, acc[cls][0]);
          acc[cls][1] = fmaf(i3[a], wv.y, acc[cls][1]);
          acc[cls][2] = fmaf(i3[a], wv.z, acc[cls][2]);
          acc[cls][3] = fmaf(i3[a], wv.w, acc[cls][3]);
        }
      }
    }
  }
#pragma unroll
  for (int cls = 0; cls < 8; ++cls) {
    const int pz = (cls >> 2) & 1, py = (cls >> 1) & 1, px = cls & 1;
    const int ovf = ((2 * vz + pz) * 16 + (2 * vy + py)) * 16 + (2 * vx + px);
#pragma unroll
    for (int j = 0; j < 4; ++j)
      out[(((size_t)b * 64 + p) * 4 + j) * 4096 + ovf] = acc[cls][j];
  }
}

extern "C" void kernel_launch(void* const* d_in, const int* in_sizes, int n_in,
                              void* d_out, int out_size, void* d_ws, size_t ws_size,
                              hipStream_t stream) {
  const float* x  = (const float*)d_in[0];
  const float* w0 = (const float*)d_in[1];
  const float* b0 = (const float*)d_in[2];
  const float* w1 = (const float*)d_in[3];
  const float* b1 = (const float*)d_in[4];
  const float* w2 = (const float*)d_in[5];
  const float* b2 = (const float*)d_in[6];
  const float* w3 = (const float*)d_in[7];
  const float* b3 = (const float*)d_in[8];
  const float* w4 = (const float*)d_in[9];
  const float* b4 = (const float*)d_in[10];

  float* ws = (float*)d_ws;
  float* h0 = ws;                               // 2048 f32
  float* h1 = h0 + 2048;                        // 1,048,576 f32
  float* h3 = h1 + 1048576;                     // 33,554,432 f32
  u16* h2hi  = (u16*)(h3 + 33554432);           // 4,194,304 u16
  u16* h2lo  = h2hi + 4194304;                  // 4,194,304 u16
  u16* wt3hi = h2lo + 4194304;                  // 16,777,216 u16
  u16* wt3lo = wt3hi + 16777216;                // 16,777,216 u16  (total ~222 MB)
  float* outp = (float*)d_out;

  k_dec0<<<dim3(16, 32), dim3(256), 0, stream>>>(x, w0, b0, h0);
  k_l1<<<dim3(512), dim3(256), 0, stream>>>(h0, w1, b1, h1);
  k_prep_w3<<<dim3(512), dim3(256), 0, stream>>>(w3, wt3hi, wt3lo);
  k_deconv_split<128, 2><<<dim3(512), dim3(256), 0, stream>>>(h1, w2, b2, h2hi, h2lo);
  k_l3_mfma<<<dim3(2048), dim3(256), 0, stream>>>(h2hi, h2lo, wt3hi, wt3lo, b3, h3);
  k_l4<<<dim3(2048), dim3(256), 0, stream>>>(h3, w4, b4, outp);
}